// Round 1
// baseline (1734.392 us; speedup 1.0000x reference)
//
#include <hip/hip_runtime.h>
#include <stdint.h>

typedef _Float16 half8  __attribute__((ext_vector_type(8)));
typedef _Float16 half4v __attribute__((ext_vector_type(4)));
typedef float   floatx4 __attribute__((ext_vector_type(4)));

#define HEADS 4
#define HID   1024
#define FDIM  4096   // IN_DIM = HEADS*HID = OUT_DIM

// ---------------- elementwise cast f32 -> f16 (vectorized x4) ----------------
__global__ void k_cast_f16(const float* __restrict__ in, _Float16* __restrict__ out, int n4)
{
  int i = blockIdx.x * 256 + threadIdx.x;
  if (i < n4) {
    float4 v = ((const float4*)in)[i];
    half4v o;
    o[0] = (_Float16)v.x; o[1] = (_Float16)v.y; o[2] = (_Float16)v.z; o[3] = (_Float16)v.w;
    ((half4v*)out)[i] = o;
  }
}

// ---------------- transpose + cast: W[K,N] f32 -> Wt[N,K] f16 ----------------
__global__ void k_trans_cast(const float* __restrict__ W, _Float16* __restrict__ Wt, int K, int N)
{
  __shared__ float tile[32][33];
  int kb = blockIdx.y * 32, nb = blockIdx.x * 32;
  int tx = threadIdx.x, ty = threadIdx.y;
  tile[ty][tx] = W[(size_t)(kb + ty) * N + nb + tx];
  __syncthreads();
  Wt[(size_t)(nb + ty) * K + kb + tx] = (_Float16)tile[tx][ty];
}

// ---------------- GEMM: C[M,N]f32 = A[M,K]f16 @ Bt[N,K]f16 ----------------
// 128x128 block tile, 4 waves in 2x2, each wave 64x64 = 4x4 MFMA 16x16x32 subtiles, BK=64.
// LDS: per operand 128 rows x 8 k-octets (16B chunks); slot s = r*8 + (q ^ (r&7))
// -> fragment reads are 2-way bank aliased (free), staging writes stride-16B (free).
__global__ __launch_bounds__(256) void k_gemm(
    const _Float16* __restrict__ A, const _Float16* __restrict__ Bt,
    float* __restrict__ C, int M, int N, int K)
{
  __shared__ _Float16 sA[8192];   // 16 KB
  __shared__ _Float16 sB[8192];   // 16 KB
  const int tid  = threadIdx.x;
  const int lane = tid & 63;
  const int wv   = tid >> 6;
  const int wm   = (wv & 1) * 64;   // wave row offset in tile
  const int wn   = (wv >> 1) * 64;  // wave col offset in tile
  const int bm0  = blockIdx.y * 128;
  const int bn0  = blockIdx.x * 128;
  const int row_m = lane & 15;      // fragment row (A) / col (B)
  const int row_q = lane >> 4;      // fragment k-quad

  floatx4 acc[4][4];
#pragma unroll
  for (int i = 0; i < 4; ++i)
#pragma unroll
    for (int j = 0; j < 4; ++j)
      acc[i][j] = (floatx4){0.f, 0.f, 0.f, 0.f};

  for (int k0 = 0; k0 < K; k0 += 64) {
    half8 va[4], vb[4];
#pragma unroll
    for (int i = 0; i < 4; ++i) {
      int s = (i * 4 + wv) * 64 + lane;   // slot in [0,1024)
      int r = s >> 3;
      int q = (s & 7) ^ (r & 7);
      int arow = bm0 + r; arow = arow < M ? arow : (M - 1);
      va[i] = *(const half8*)(A  + (size_t)arow * K + k0 + q * 8);
      vb[i] = *(const half8*)(Bt + (size_t)(bn0 + r) * K + k0 + q * 8);
    }
    __syncthreads();   // previous compute done reading LDS
#pragma unroll
    for (int i = 0; i < 4; ++i) {
      int s = (i * 4 + wv) * 64 + lane;
      *(half8*)(sA + s * 8) = va[i];
      *(half8*)(sB + s * 8) = vb[i];
    }
    __syncthreads();   // staging complete

#pragma unroll
    for (int kk = 0; kk < 2; ++kk) {
      half8 af[4], bf[4];
      int qa = kk * 4 + row_q;
#pragma unroll
      for (int i = 0; i < 4; ++i) {
        int ra = wm + i * 16 + row_m;
        af[i] = *(const half8*)(sA + (ra * 8 + (qa ^ (ra & 7))) * 8);
        int rb = wn + i * 16 + row_m;
        bf[i] = *(const half8*)(sB + (rb * 8 + (qa ^ (rb & 7))) * 8);
      }
#pragma unroll
      for (int mi = 0; mi < 4; ++mi)
#pragma unroll
        for (int ni = 0; ni < 4; ++ni)
          acc[mi][ni] = __builtin_amdgcn_mfma_f32_16x16x32_f16(af[mi], bf[ni], acc[mi][ni], 0, 0, 0);
    }
  }

  // Epilogue. D layout: col = lane&15, row = (lane>>4)*4 + reg  [verified m89/m91]
#pragma unroll
  for (int mi = 0; mi < 4; ++mi) {
#pragma unroll
    for (int ni = 0; ni < 4; ++ni) {
      int row0 = bm0 + wm + mi * 16 + row_q * 4;
      int colg = bn0 + wn + ni * 16 + row_m;
#pragma unroll
      for (int r = 0; r < 4; ++r) {
        int row = row0 + r;
        if (row < M) C[(size_t)row * N + colg] = acc[mi][ni][r];
      }
    }
  }
}

// ---------------- attention scores: a_src/a_dst [n, HEADS] ----------------
__global__ void k_attn_scores(const float* __restrict__ H, const float* __restrict__ att_s,
                              const float* __restrict__ att_d, float* __restrict__ a_src,
                              float* __restrict__ a_dst)
{
  int node = blockIdx.x;
  int t = threadIdx.x;
  int head = t >> 6;         // one wave per head
  int lc = t & 63;
  const float* hrow = H + (size_t)node * FDIM + head * HID;
  const float* as = att_s + head * HID;
  const float* ad = att_d + head * HID;
  float s1 = 0.f, s2 = 0.f;
  for (int c = lc; c < HID; c += 64) {
    float v = hrow[c];
    s1 += v * as[c];
    s2 += v * ad[c];
  }
#pragma unroll
  for (int off = 32; off; off >>= 1) { s1 += __shfl_down(s1, off); s2 += __shfl_down(s2, off); }
  if (lc == 0) {
    a_src[node * HEADS + head] = s1;
    a_dst[node * HEADS + head] = s2;
  }
}

// ---------------- CSR build ----------------
__global__ void k_fill_deg(int* deg, int n)
{
  int i = blockIdx.x * 256 + threadIdx.x;
  if (i < n) deg[i] = 1;   // self-loop
}
__global__ void k_hist(const int* __restrict__ ei, int* deg, int E)
{
  int e = blockIdx.x * 256 + threadIdx.x;
  if (e < E) atomicAdd(&deg[ei[E + e]], 1);   // dst row
}
__global__ void k_scan(const int* __restrict__ deg, int* __restrict__ rowptr, int n)
{
  __shared__ int buf[1024];
  __shared__ int carry;
  int t = threadIdx.x;
  if (t == 0) { carry = 0; rowptr[0] = 0; }
  __syncthreads();
  for (int base = 0; base < n; base += 1024) {
    int v = (base + t < n) ? deg[base + t] : 0;
    buf[t] = v;
    __syncthreads();
    for (int off = 1; off < 1024; off <<= 1) {
      int x = (t >= off) ? buf[t - off] : 0;
      __syncthreads();
      buf[t] += x;
      __syncthreads();
    }
    if (base + t < n) rowptr[base + t + 1] = carry + buf[t];
    __syncthreads();
    if (t == 0) carry += buf[1023];
    __syncthreads();
  }
}
__global__ void k_copy_i32(const int* __restrict__ a, int* __restrict__ b, int n)
{
  int i = blockIdx.x * 256 + threadIdx.x;
  if (i < n) b[i] = a[i];
}
__global__ void k_fill(const int* __restrict__ ei, int* cursor, int* __restrict__ col, int E, int n)
{
  int i = blockIdx.x * 256 + threadIdx.x;
  if (i < E) {
    int s = ei[i], d = ei[E + i];
    int pos = atomicAdd(&cursor[d], 1);
    col[pos] = s;
  } else if (i < E + n) {
    int v = i - E;
    int pos = atomicAdd(&cursor[v], 1);
    col[pos] = v;
  }
}

// ---------------- per-(dst,head) softmax stats: amax, denom ----------------
__global__ void k_stats(const float* __restrict__ a_src, const float* __restrict__ a_dst,
                        const int* __restrict__ rowptr, const int* __restrict__ col,
                        float* __restrict__ amax, float* __restrict__ den)
{
  int d = blockIdx.x;
  int lane = threadIdx.x;      // 64
  int h = lane & 3;
  int sub = lane >> 2;         // 16 workers per head
  int s0 = rowptr[d], s1 = rowptr[d + 1];
  float ad = a_dst[d * HEADS + h];
  float mx = -1e30f;
  for (int e = s0 + sub; e < s1; e += 16) {
    float al = a_src[col[e] * HEADS + h] + ad;
    al = al > 0.f ? al : 0.2f * al;
    mx = fmaxf(mx, al);
  }
#pragma unroll
  for (int off = 4; off < 64; off <<= 1) mx = fmaxf(mx, __shfl_xor(mx, off));
  float sm = 0.f;
  for (int e = s0 + sub; e < s1; e += 16) {
    float al = a_src[col[e] * HEADS + h] + ad;
    al = al > 0.f ? al : 0.2f * al;
    sm += __expf(al - mx);
  }
#pragma unroll
  for (int off = 4; off < 64; off <<= 1) sm += __shfl_xor(sm, off);
  if (lane < 4) {
    amax[d * HEADS + h] = mx;
    den[d * HEADS + h] = sm;
  }
}

// ---------------- aggregation + head-mean + bias + ELU -> f16 [n, HID] ----------------
__global__ __launch_bounds__(256) void k_aggregate(
    const float* __restrict__ H, const int* __restrict__ rowptr, const int* __restrict__ col,
    const float* __restrict__ a_src, const float* __restrict__ a_dst,
    const float* __restrict__ amax, const float* __restrict__ den,
    const float* __restrict__ bias, _Float16* __restrict__ out)
{
  int d = blockIdx.x;
  int t = threadIdx.x;
  __shared__ float wls[64 * HEADS];
  __shared__ int srcs[64];
  float acc0 = 0.f, acc1 = 0.f, acc2 = 0.f, acc3 = 0.f;
  int s0 = rowptr[d], s1 = rowptr[d + 1];
  for (int base = s0; base < s1; base += 64) {
    int m = min(64, s1 - base);
    __syncthreads();
    if (t < m * HEADS) {
      int j = t >> 2, h = t & 3;
      int s = col[base + j];
      if (h == 0) srcs[j] = s;
      float al = a_src[s * HEADS + h] + a_dst[d * HEADS + h];
      al = al > 0.f ? al : 0.2f * al;
      wls[t] = __expf(al - amax[d * HEADS + h]) / den[d * HEADS + h];
    }
    __syncthreads();
    for (int j = 0; j < m; ++j) {
      const float4* hp = (const float4*)(H + (size_t)srcs[j] * FDIM);
      float w0 = wls[j * 4 + 0], w1 = wls[j * 4 + 1], w2 = wls[j * 4 + 2], w3 = wls[j * 4 + 3];
      float4 v0 = hp[t], v1 = hp[256 + t], v2 = hp[512 + t], v3 = hp[768 + t];
      acc0 += w0 * v0.x + w1 * v1.x + w2 * v2.x + w3 * v3.x;
      acc1 += w0 * v0.y + w1 * v1.y + w2 * v2.y + w3 * v3.y;
      acc2 += w0 * v0.z + w1 * v1.z + w2 * v2.z + w3 * v3.z;
      acc3 += w0 * v0.w + w1 * v1.w + w2 * v2.w + w3 * v3.w;
    }
  }
  float4 b = ((const float4*)bias)[t];
  float o0 = 0.25f * acc0 + b.x;
  float o1 = 0.25f * acc1 + b.y;
  float o2 = 0.25f * acc2 + b.z;
  float o3 = 0.25f * acc3 + b.w;
  o0 = o0 > 0.f ? o0 : expm1f(o0);
  o1 = o1 > 0.f ? o1 : expm1f(o1);
  o2 = o2 > 0.f ? o2 : expm1f(o2);
  o3 = o3 > 0.f ? o3 : expm1f(o3);
  half4v o;
  o[0] = (_Float16)o0; o[1] = (_Float16)o1; o[2] = (_Float16)o2; o[3] = (_Float16)o3;
  *(half4v*)(out + (size_t)d * HID + t * 4) = o;
}

// ---------------- block reduction helper ----------------
__device__ __forceinline__ float block_sum256(float v, float* red)
{
#pragma unroll
  for (int off = 32; off; off >>= 1) v += __shfl_down(v, off);
  int lane = threadIdx.x & 63, w = threadIdx.x >> 6;
  __syncthreads();
  if (lane == 0) red[w] = v;
  __syncthreads();
  return red[0] + red[1] + red[2] + red[3];
}

// ---------------- bias + LayerNorm + L2 normalize ----------------
__global__ __launch_bounds__(256) void k_ln_l2(
    const float* __restrict__ Y, const float* __restrict__ bp,
    const float* __restrict__ gamma, const float* __restrict__ beta,
    float* __restrict__ out)
{
  __shared__ float red[4];
  int row = blockIdx.x;
  int t = threadIdx.x;
  const float4* yp = (const float4*)(Y + (size_t)row * FDIM);
  const float4* bpp = (const float4*)bp;
  float4 v[4];
  float s = 0.f;
#pragma unroll
  for (int i = 0; i < 4; ++i) {
    float4 a = yp[t + 256 * i];
    float4 b = bpp[t + 256 * i];
    a.x += b.x; a.y += b.y; a.z += b.z; a.w += b.w;
    v[i] = a;
    s += a.x + a.y + a.z + a.w;
  }
  float mu = block_sum256(s, red) * (1.f / FDIM);
  float sq = 0.f;
#pragma unroll
  for (int i = 0; i < 4; ++i) {
    float dx = v[i].x - mu, dy = v[i].y - mu, dz = v[i].z - mu, dw = v[i].w - mu;
    sq += dx * dx + dy * dy + dz * dz + dw * dw;
  }
  float var = block_sum256(sq, red) * (1.f / FDIM);
  float rstd = rsqrtf(var + 1e-5f);
  float ss = 0.f;
#pragma unroll
  for (int i = 0; i < 4; ++i) {
    float4 g = ((const float4*)gamma)[t + 256 * i];
    float4 bt = ((const float4*)beta)[t + 256 * i];
    v[i].x = (v[i].x - mu) * rstd * g.x + bt.x;
    v[i].y = (v[i].y - mu) * rstd * g.y + bt.y;
    v[i].z = (v[i].z - mu) * rstd * g.z + bt.z;
    v[i].w = (v[i].w - mu) * rstd * g.w + bt.w;
    ss += v[i].x * v[i].x + v[i].y * v[i].y + v[i].z * v[i].z + v[i].w * v[i].w;
  }
  float nrm = sqrtf(block_sum256(ss, red));
  float inv = 1.f / fmaxf(nrm, 1e-12f);
  float4* op = (float4*)(out + (size_t)row * FDIM);
#pragma unroll
  for (int i = 0; i < 4; ++i) {
    float4 o;
    o.x = v[i].x * inv; o.y = v[i].y * inv; o.z = v[i].z * inv; o.w = v[i].w * inv;
    op[t + 256 * i] = o;
  }
}

// ---------------- launch ----------------
extern "C" void kernel_launch(void* const* d_in, const int* in_sizes, int n_in,
                              void* d_out, int out_size, void* d_ws, size_t ws_size,
                              hipStream_t stream)
{
  const float* x        = (const float*)d_in[0];
  const int*   ei       = (const int*)d_in[1];
  const float* W1       = (const float*)d_in[2];
  const float* att1_src = (const float*)d_in[3];
  const float* att1_dst = (const float*)d_in[4];
  const float* b1       = (const float*)d_in[5];
  const float* W2       = (const float*)d_in[6];
  const float* att2_src = (const float*)d_in[7];
  const float* att2_dst = (const float*)d_in[8];
  const float* b2       = (const float*)d_in[9];
  const float* Wp       = (const float*)d_in[10];
  const float* bp       = (const float*)d_in[11];
  const float* gamma    = (const float*)d_in[12];
  const float* beta     = (const float*)d_in[13];

  const int n = in_sizes[0] / FDIM;   // 10000
  const int E = in_sizes[1] / 2;      // 100000

  char* p = (char*)d_ws;
  auto alloc = [&](size_t b) { char* r = p; p += (b + 255) & ~(size_t)255; return r; };
  _Float16* xh  = (_Float16*)alloc((size_t)n * FDIM * 2);
  _Float16* w1t = (_Float16*)alloc((size_t)FDIM * FDIM * 2);
  _Float16* w2t = (_Float16*)alloc((size_t)FDIM * HID * 2);
  _Float16* wpt = (_Float16*)alloc((size_t)FDIM * HID * 2);
  float*    H   = (float*)alloc((size_t)n * FDIM * 4);
  _Float16* lh  = (_Float16*)alloc((size_t)n * HID * 2);
  float*    a_src = (float*)alloc((size_t)n * HEADS * 4);
  float*    a_dst = (float*)alloc((size_t)n * HEADS * 4);
  float*    amax  = (float*)alloc((size_t)n * HEADS * 4);
  float*    den   = (float*)alloc((size_t)n * HEADS * 4);
  int* deg    = (int*)alloc((size_t)n * 4);
  int* rowptr = (int*)alloc((size_t)(n + 1) * 4);
  int* cursor = (int*)alloc((size_t)n * 4);
  int* col    = (int*)alloc((size_t)(E + n) * 4);

  // input casts / weight transposes
  k_cast_f16<<<(n * FDIM / 4 + 255) / 256, 256, 0, stream>>>(x, xh, n * FDIM / 4);
  k_trans_cast<<<dim3(FDIM / 32, FDIM / 32), dim3(32, 32), 0, stream>>>(W1, w1t, FDIM, FDIM);
  k_trans_cast<<<dim3(FDIM / 32, HID / 32), dim3(32, 32), 0, stream>>>(W2, w2t, HID, FDIM);
  k_trans_cast<<<dim3(FDIM / 32, HID / 32), dim3(32, 32), 0, stream>>>(Wp, wpt, HID, FDIM);

  // CSR by dst (self-loops included), reused for both layers
  k_fill_deg<<<(n + 255) / 256, 256, 0, stream>>>(deg, n);
  k_hist<<<(E + 255) / 256, 256, 0, stream>>>(ei, deg, E);
  k_scan<<<1, 1024, 0, stream>>>(deg, rowptr, n);
  k_copy_i32<<<(n + 255) / 256, 256, 0, stream>>>(rowptr, cursor, n);
  k_fill<<<(E + n + 255) / 256, 256, 0, stream>>>(ei, cursor, col, E, n);

  dim3 ggrid(FDIM / 128, (n + 127) / 128);

  // Layer 1
  k_gemm<<<ggrid, 256, 0, stream>>>(xh, w1t, H, n, FDIM, FDIM);
  k_attn_scores<<<n, 256, 0, stream>>>(H, att1_src, att1_dst, a_src, a_dst);
  k_stats<<<n, 64, 0, stream>>>(a_src, a_dst, rowptr, col, amax, den);
  k_aggregate<<<n, 256, 0, stream>>>(H, rowptr, col, a_src, a_dst, amax, den, b1, lh);

  // Layer 2
  k_gemm<<<ggrid, 256, 0, stream>>>(lh, w2t, H, n, FDIM, HID);
  k_attn_scores<<<n, 256, 0, stream>>>(H, att2_src, att2_dst, a_src, a_dst);
  k_stats<<<n, 64, 0, stream>>>(a_src, a_dst, rowptr, col, amax, den);
  k_aggregate<<<n, 256, 0, stream>>>(H, rowptr, col, a_src, a_dst, amax, den, b2, lh);

  // Projection + LayerNorm + L2 normalize
  k_gemm<<<ggrid, 256, 0, stream>>>(lh, wpt, H, n, FDIM, HID);
  k_ln_l2<<<n, 256, 0, stream>>>(H, bp, gamma, beta, (float*)d_out);
}

// Round 2
// 1358.273 us; speedup vs baseline: 1.2769x; 1.2769x over previous
//
#include <hip/hip_runtime.h>
#include <stdint.h>

typedef _Float16 half8  __attribute__((ext_vector_type(8)));
typedef _Float16 half4v __attribute__((ext_vector_type(4)));
typedef float   floatx4 __attribute__((ext_vector_type(4)));

#define HEADS 4
#define HID   1024
#define FDIM  4096   // IN_DIM = HEADS*HID = OUT_DIM

// async global->LDS 16B: lane writes lds_base + lane*16 (wave-uniform base).
__device__ __forceinline__ void gl_lds16(const _Float16* g, _Float16* l)
{
  __builtin_amdgcn_global_load_lds(
      (const __attribute__((address_space(1))) void*)g,
      (__attribute__((address_space(3))) void*)l,
      16, 0, 0);
}

// ---------------- elementwise cast f32 -> f16 (vectorized x4) ----------------
__global__ void k_cast_f16(const float* __restrict__ in, _Float16* __restrict__ out, int n4)
{
  int i = blockIdx.x * 256 + threadIdx.x;
  if (i < n4) {
    float4 v = ((const float4*)in)[i];
    half4v o;
    o[0] = (_Float16)v.x; o[1] = (_Float16)v.y; o[2] = (_Float16)v.z; o[3] = (_Float16)v.w;
    ((half4v*)out)[i] = o;
  }
}

// ---------------- transpose + cast: W[K,N] f32 -> Wt[N,K] f16 ----------------
__global__ void k_trans_cast(const float* __restrict__ W, _Float16* __restrict__ Wt, int K, int N)
{
  __shared__ float tile[32][33];
  int kb = blockIdx.y * 32, nb = blockIdx.x * 32;
  int tx = threadIdx.x, ty = threadIdx.y;
  tile[ty][tx] = W[(size_t)(kb + ty) * N + nb + tx];
  __syncthreads();
  Wt[(size_t)(nb + ty) * K + kb + tx] = (_Float16)tile[tx][ty];
}

// ---------------- GEMM: C[M,N]f16 = A[M,K]f16 @ Bt[N,K]f16 ----------------
// 128x128 tile, 4 waves 2x2, wave = 4x4 of 16x16x32 MFMA, BK=64.
// LDS slot s = r*8 + (q ^ (r&7)); transport = global_load_lds dwordx4 with the
// swizzle inverse applied to the GLOBAL address (lane->slot map is hw-fixed).
__global__ __launch_bounds__(256) void k_gemm(
    const _Float16* __restrict__ A, const _Float16* __restrict__ Bt,
    _Float16* __restrict__ C, int M, int N, int K)
{
  __shared__ _Float16 sA[8192];   // 16 KB
  __shared__ _Float16 sB[8192];   // 16 KB
  const int tid  = threadIdx.x;
  const int lane = tid & 63;
  const int wv   = tid >> 6;
  const int wm   = (wv & 1) * 64;
  const int wn   = (wv >> 1) * 64;
  const int bm0  = blockIdx.y * 128;
  const int bn0  = blockIdx.x * 128;
  const int row_m = lane & 15;
  const int row_q = lane >> 4;

  // per-lane global offsets for this wave's 4 staging slots (swizzle inverse)
  size_t aoff[4], boff[4];
#pragma unroll
  for (int i = 0; i < 4; ++i) {
    int s = (i * 4 + wv) * 64 + lane;
    int r = s >> 3;
    int q = (s & 7) ^ (r & 7);
    int arow = bm0 + r; arow = arow < M ? arow : (M - 1);
    aoff[i] = (size_t)arow * K + q * 8;
    boff[i] = (size_t)(bn0 + r) * K + q * 8;
  }

  floatx4 acc[4][4];
#pragma unroll
  for (int i = 0; i < 4; ++i)
#pragma unroll
    for (int j = 0; j < 4; ++j)
      acc[i][j] = (floatx4){0.f, 0.f, 0.f, 0.f};

  for (int k0 = 0; k0 < K; k0 += 64) {
    __syncthreads();   // previous compute done reading LDS
#pragma unroll
    for (int i = 0; i < 4; ++i) {
      gl_lds16(A  + aoff[i] + k0, sA + (i * 4 + wv) * 512);
      gl_lds16(Bt + boff[i] + k0, sB + (i * 4 + wv) * 512);
    }
    __syncthreads();   // vmcnt drained -> staging complete

#pragma unroll
    for (int kk = 0; kk < 2; ++kk) {
      half8 af[4], bf[4];
      int qa = kk * 4 + row_q;
#pragma unroll
      for (int i = 0; i < 4; ++i) {
        int ra = wm + i * 16 + row_m;
        af[i] = *(const half8*)(sA + (ra * 8 + (qa ^ (ra & 7))) * 8);
        int rb = wn + i * 16 + row_m;
        bf[i] = *(const half8*)(sB + (rb * 8 + (qa ^ (rb & 7))) * 8);
      }
#pragma unroll
      for (int mi = 0; mi < 4; ++mi)
#pragma unroll
        for (int ni = 0; ni < 4; ++ni)
          acc[mi][ni] = __builtin_amdgcn_mfma_f32_16x16x32_f16(af[mi], bf[ni], acc[mi][ni], 0, 0, 0);
    }
  }

  // D layout: col = lane&15, row = (lane>>4)*4 + reg
#pragma unroll
  for (int mi = 0; mi < 4; ++mi) {
#pragma unroll
    for (int ni = 0; ni < 4; ++ni) {
      int row0 = bm0 + wm + mi * 16 + row_q * 4;
      int colg = bn0 + wn + ni * 16 + row_m;
#pragma unroll
      for (int r = 0; r < 4; ++r) {
        int row = row0 + r;
        if (row < M) C[(size_t)row * N + colg] = (_Float16)acc[mi][ni][r];
      }
    }
  }
}

// ---------------- attention scores from f16 H ----------------
__global__ void k_attn_scores(const _Float16* __restrict__ H, const float* __restrict__ att_s,
                              const float* __restrict__ att_d, float* __restrict__ a_src,
                              float* __restrict__ a_dst)
{
  int node = blockIdx.x;
  int t = threadIdx.x;
  int head = t >> 6;         // one wave per head
  int lc = t & 63;
  const half8* hp = (const half8*)(H + (size_t)node * FDIM + head * HID);
  const float* as = att_s + head * HID;
  const float* ad = att_d + head * HID;
  float s1 = 0.f, s2 = 0.f;
#pragma unroll
  for (int u = 0; u < 2; ++u) {
    half8 v = hp[lc * 2 + u];
    int base = (lc * 2 + u) * 8;
#pragma unroll
    for (int e = 0; e < 8; ++e) {
      float f = (float)v[e];
      s1 += f * as[base + e];
      s2 += f * ad[base + e];
    }
  }
#pragma unroll
  for (int off = 32; off; off >>= 1) { s1 += __shfl_down(s1, off); s2 += __shfl_down(s2, off); }
  if (lc == 0) {
    a_src[node * HEADS + head] = s1;
    a_dst[node * HEADS + head] = s2;
  }
}

// ---------------- CSR build ----------------
__global__ void k_fill_deg(int* deg, int n)
{
  int i = blockIdx.x * 256 + threadIdx.x;
  if (i < n) deg[i] = 1;   // self-loop
}
__global__ void k_hist(const int* __restrict__ ei, int* deg, int E)
{
  int e = blockIdx.x * 256 + threadIdx.x;
  if (e < E) atomicAdd(&deg[ei[E + e]], 1);   // dst row
}
__global__ void k_scan(const int* __restrict__ deg, int* __restrict__ rowptr, int n)
{
  __shared__ int buf[1024];
  __shared__ int carry;
  int t = threadIdx.x;
  if (t == 0) { carry = 0; rowptr[0] = 0; }
  __syncthreads();
  for (int base = 0; base < n; base += 1024) {
    int v = (base + t < n) ? deg[base + t] : 0;
    buf[t] = v;
    __syncthreads();
    for (int off = 1; off < 1024; off <<= 1) {
      int x = (t >= off) ? buf[t - off] : 0;
      __syncthreads();
      buf[t] += x;
      __syncthreads();
    }
    if (base + t < n) rowptr[base + t + 1] = carry + buf[t];
    __syncthreads();
    if (t == 0) carry += buf[1023];
    __syncthreads();
  }
}
__global__ void k_copy_i32(const int* __restrict__ a, int* __restrict__ b, int n)
{
  int i = blockIdx.x * 256 + threadIdx.x;
  if (i < n) b[i] = a[i];
}
__global__ void k_fill(const int* __restrict__ ei, int* cursor, int* __restrict__ col, int E, int n)
{
  int i = blockIdx.x * 256 + threadIdx.x;
  if (i < E) {
    int s = ei[i], d = ei[E + i];
    int pos = atomicAdd(&cursor[d], 1);
    col[pos] = s;
  } else if (i < E + n) {
    int v = i - E;
    int pos = atomicAdd(&cursor[v], 1);
    col[pos] = v;
  }
}

// ---------------- per-(dst,head) softmax stats: amax, denom ----------------
__global__ void k_stats(const float* __restrict__ a_src, const float* __restrict__ a_dst,
                        const int* __restrict__ rowptr, const int* __restrict__ col,
                        float* __restrict__ amax, float* __restrict__ den)
{
  int d = blockIdx.x;
  int lane = threadIdx.x;      // 64
  int h = lane & 3;
  int sub = lane >> 2;         // 16 workers per head
  int s0 = rowptr[d], s1 = rowptr[d + 1];
  float ad = a_dst[d * HEADS + h];
  float mx = -1e30f;
  for (int e = s0 + sub; e < s1; e += 16) {
    float al = a_src[col[e] * HEADS + h] + ad;
    al = al > 0.f ? al : 0.2f * al;
    mx = fmaxf(mx, al);
  }
#pragma unroll
  for (int off = 4; off < 64; off <<= 1) mx = fmaxf(mx, __shfl_xor(mx, off));
  float sm = 0.f;
  for (int e = s0 + sub; e < s1; e += 16) {
    float al = a_src[col[e] * HEADS + h] + ad;
    al = al > 0.f ? al : 0.2f * al;
    sm += __expf(al - mx);
  }
#pragma unroll
  for (int off = 4; off < 64; off <<= 1) sm += __shfl_xor(sm, off);
  if (lane < 4) {
    amax[d * HEADS + h] = mx;
    den[d * HEADS + h] = sm;
  }
}

// ---------------- aggregation + head-mean + bias + ELU -> f16 [n, HID] ----------------
__global__ __launch_bounds__(256) void k_aggregate(
    const _Float16* __restrict__ H, const int* __restrict__ rowptr, const int* __restrict__ col,
    const float* __restrict__ a_src, const float* __restrict__ a_dst,
    const float* __restrict__ amax, const float* __restrict__ den,
    const float* __restrict__ bias, _Float16* __restrict__ out)
{
  int d = blockIdx.x;
  int t = threadIdx.x;
  __shared__ float wls[64 * HEADS];
  __shared__ int srcs[64];
  float acc0 = 0.f, acc1 = 0.f, acc2 = 0.f, acc3 = 0.f;
  int s0 = rowptr[d], s1 = rowptr[d + 1];
  for (int base = s0; base < s1; base += 64) {
    int m = min(64, s1 - base);
    __syncthreads();
    if (t < m * HEADS) {
      int j = t >> 2, h = t & 3;
      int s = col[base + j];
      if (h == 0) srcs[j] = s;
      float al = a_src[s * HEADS + h] + a_dst[d * HEADS + h];
      al = al > 0.f ? al : 0.2f * al;
      wls[t] = __expf(al - amax[d * HEADS + h]) / den[d * HEADS + h];
    }
    __syncthreads();
    for (int j = 0; j < m; ++j) {
      const half4v* hp = (const half4v*)(H + (size_t)srcs[j] * FDIM);
      float w0 = wls[j * 4 + 0], w1 = wls[j * 4 + 1], w2 = wls[j * 4 + 2], w3 = wls[j * 4 + 3];
      half4v v0 = hp[t], v1 = hp[256 + t], v2 = hp[512 + t], v3 = hp[768 + t];
      acc0 += w0 * (float)v0[0] + w1 * (float)v1[0] + w2 * (float)v2[0] + w3 * (float)v3[0];
      acc1 += w0 * (float)v0[1] + w1 * (float)v1[1] + w2 * (float)v2[1] + w3 * (float)v3[1];
      acc2 += w0 * (float)v0[2] + w1 * (float)v1[2] + w2 * (float)v2[2] + w3 * (float)v3[2];
      acc3 += w0 * (float)v0[3] + w1 * (float)v1[3] + w2 * (float)v2[3] + w3 * (float)v3[3];
    }
  }
  float4 b = ((const float4*)bias)[t];
  float o0 = 0.25f * acc0 + b.x;
  float o1 = 0.25f * acc1 + b.y;
  float o2 = 0.25f * acc2 + b.z;
  float o3 = 0.25f * acc3 + b.w;
  o0 = o0 > 0.f ? o0 : expm1f(o0);
  o1 = o1 > 0.f ? o1 : expm1f(o1);
  o2 = o2 > 0.f ? o2 : expm1f(o2);
  o3 = o3 > 0.f ? o3 : expm1f(o3);
  half4v o;
  o[0] = (_Float16)o0; o[1] = (_Float16)o1; o[2] = (_Float16)o2; o[3] = (_Float16)o3;
  *(half4v*)(out + (size_t)d * HID + t * 4) = o;
}

// ---------------- block reduction helper ----------------
__device__ __forceinline__ float block_sum256(float v, float* red)
{
#pragma unroll
  for (int off = 32; off; off >>= 1) v += __shfl_down(v, off);
  int lane = threadIdx.x & 63, w = threadIdx.x >> 6;
  __syncthreads();
  if (lane == 0) red[w] = v;
  __syncthreads();
  return red[0] + red[1] + red[2] + red[3];
}

// ---------------- bias + LayerNorm + L2 normalize (Y in f16) ----------------
__global__ __launch_bounds__(256) void k_ln_l2(
    const _Float16* __restrict__ Y, const float* __restrict__ bp,
    const float* __restrict__ gamma, const float* __restrict__ beta,
    float* __restrict__ out)
{
  __shared__ float red[4];
  int row = blockIdx.x;
  int t = threadIdx.x;
  const half4v* yp = (const half4v*)(Y + (size_t)row * FDIM);
  const float4* bpp = (const float4*)bp;
  float4 v[4];
  float s = 0.f;
#pragma unroll
  for (int i = 0; i < 4; ++i) {
    half4v a = yp[t + 256 * i];
    float4 b = bpp[t + 256 * i];
    float4 f;
    f.x = (float)a[0] + b.x; f.y = (float)a[1] + b.y;
    f.z = (float)a[2] + b.z; f.w = (float)a[3] + b.w;
    v[i] = f;
    s += f.x + f.y + f.z + f.w;
  }
  float mu = block_sum256(s, red) * (1.f / FDIM);
  float sq = 0.f;
#pragma unroll
  for (int i = 0; i < 4; ++i) {
    float dx = v[i].x - mu, dy = v[i].y - mu, dz = v[i].z - mu, dw = v[i].w - mu;
    sq += dx * dx + dy * dy + dz * dz + dw * dw;
  }
  float var = block_sum256(sq, red) * (1.f / FDIM);
  float rstd = rsqrtf(var + 1e-5f);
  float ss = 0.f;
#pragma unroll
  for (int i = 0; i < 4; ++i) {
    float4 g = ((const float4*)gamma)[t + 256 * i];
    float4 bt = ((const float4*)beta)[t + 256 * i];
    v[i].x = (v[i].x - mu) * rstd * g.x + bt.x;
    v[i].y = (v[i].y - mu) * rstd * g.y + bt.y;
    v[i].z = (v[i].z - mu) * rstd * g.z + bt.z;
    v[i].w = (v[i].w - mu) * rstd * g.w + bt.w;
    ss += v[i].x * v[i].x + v[i].y * v[i].y + v[i].z * v[i].z + v[i].w * v[i].w;
  }
  float nrm = sqrtf(block_sum256(ss, red));
  float inv = 1.f / fmaxf(nrm, 1e-12f);
  float4* op = (float4*)(out + (size_t)row * FDIM);
#pragma unroll
  for (int i = 0; i < 4; ++i) {
    float4 o;
    o.x = v[i].x * inv; o.y = v[i].y * inv; o.z = v[i].z * inv; o.w = v[i].w * inv;
    op[t + 256 * i] = o;
  }
}

// ---------------- launch ----------------
extern "C" void kernel_launch(void* const* d_in, const int* in_sizes, int n_in,
                              void* d_out, int out_size, void* d_ws, size_t ws_size,
                              hipStream_t stream)
{
  const float* x        = (const float*)d_in[0];
  const int*   ei       = (const int*)d_in[1];
  const float* W1       = (const float*)d_in[2];
  const float* att1_src = (const float*)d_in[3];
  const float* att1_dst = (const float*)d_in[4];
  const float* b1       = (const float*)d_in[5];
  const float* W2       = (const float*)d_in[6];
  const float* att2_src = (const float*)d_in[7];
  const float* att2_dst = (const float*)d_in[8];
  const float* b2       = (const float*)d_in[9];
  const float* Wp       = (const float*)d_in[10];
  const float* bp       = (const float*)d_in[11];
  const float* gamma    = (const float*)d_in[12];
  const float* beta     = (const float*)d_in[13];

  const int n = in_sizes[0] / FDIM;   // 10000
  const int E = in_sizes[1] / 2;      // 100000

  char* p = (char*)d_ws;
  auto alloc = [&](size_t b) { char* r = p; p += (b + 255) & ~(size_t)255; return r; };
  _Float16* xh  = (_Float16*)alloc((size_t)n * FDIM * 2);
  _Float16* w1t = (_Float16*)alloc((size_t)FDIM * FDIM * 2);
  _Float16* w2t = (_Float16*)alloc((size_t)FDIM * HID * 2);
  _Float16* wpt = (_Float16*)alloc((size_t)FDIM * HID * 2);
  _Float16* H   = (_Float16*)alloc((size_t)n * FDIM * 2);
  _Float16* lh  = (_Float16*)alloc((size_t)n * HID * 2);
  float*    a_src = (float*)alloc((size_t)n * HEADS * 4);
  float*    a_dst = (float*)alloc((size_t)n * HEADS * 4);
  float*    amax  = (float*)alloc((size_t)n * HEADS * 4);
  float*    den   = (float*)alloc((size_t)n * HEADS * 4);
  int* deg    = (int*)alloc((size_t)n * 4);
  int* rowptr = (int*)alloc((size_t)(n + 1) * 4);
  int* cursor = (int*)alloc((size_t)n * 4);
  int* col    = (int*)alloc((size_t)(E + n) * 4);

  // input casts / weight transposes
  k_cast_f16<<<(n * FDIM / 4 + 255) / 256, 256, 0, stream>>>(x, xh, n * FDIM / 4);
  k_trans_cast<<<dim3(FDIM / 32, FDIM / 32), dim3(32, 32), 0, stream>>>(W1, w1t, FDIM, FDIM);
  k_trans_cast<<<dim3(FDIM / 32, HID / 32), dim3(32, 32), 0, stream>>>(W2, w2t, HID, FDIM);
  k_trans_cast<<<dim3(FDIM / 32, HID / 32), dim3(32, 32), 0, stream>>>(Wp, wpt, HID, FDIM);

  // CSR by dst (self-loops included), reused for both layers
  k_fill_deg<<<(n + 255) / 256, 256, 0, stream>>>(deg, n);
  k_hist<<<(E + 255) / 256, 256, 0, stream>>>(ei, deg, E);
  k_scan<<<1, 1024, 0, stream>>>(deg, rowptr, n);
  k_copy_i32<<<(n + 255) / 256, 256, 0, stream>>>(rowptr, cursor, n);
  k_fill<<<(E + n + 255) / 256, 256, 0, stream>>>(ei, cursor, col, E, n);

  dim3 ggrid(FDIM / 128, (n + 127) / 128);

  // Layer 1
  k_gemm<<<ggrid, 256, 0, stream>>>(xh, w1t, H, n, FDIM, FDIM);
  k_attn_scores<<<n, 256, 0, stream>>>(H, att1_src, att1_dst, a_src, a_dst);
  k_stats<<<n, 64, 0, stream>>>(a_src, a_dst, rowptr, col, amax, den);
  k_aggregate<<<n, 256, 0, stream>>>(H, rowptr, col, a_src, a_dst, amax, den, b1, lh);

  // Layer 2
  k_gemm<<<ggrid, 256, 0, stream>>>(lh, w2t, H, n, HID == FDIM ? HID : FDIM, HID);
  k_attn_scores<<<n, 256, 0, stream>>>(H, att2_src, att2_dst, a_src, a_dst);
  k_stats<<<n, 64, 0, stream>>>(a_src, a_dst, rowptr, col, amax, den);
  k_aggregate<<<n, 256, 0, stream>>>(H, rowptr, col, a_src, a_dst, amax, den, b2, lh);

  // Projection + LayerNorm + L2 normalize
  k_gemm<<<ggrid, 256, 0, stream>>>(lh, wpt, H, n, FDIM, HID);
  k_ln_l2<<<n, 256, 0, stream>>>(H, bp, gamma, beta, (float*)d_out);
}